// Round 5
// baseline (1193.697 us; speedup 1.0000x reference)
//
#include <hip/hip_runtime.h>
#include <math.h>

#define NN 50000
#define EE 800000
#define SCAN_B 196   // ceil(50000/256)
#define NPB 128      // nodes per node_linear block
#define NLT 320      // node_linear threads (5 waves, one per matrix)

// ---------- sort phase: CSR by dst ----------
__global__ __launch_bounds__(256) void k_hist(const int* __restrict__ ei,
                                              int* __restrict__ deg) {
    int i = blockIdx.x * 256 + threadIdx.x;
    if (i < EE) atomicAdd(&deg[ei[EE + i]], 1);
}

__global__ __launch_bounds__(256) void k_scanA(const int* __restrict__ deg,
                                               int* __restrict__ loc,
                                               int* __restrict__ bsum) {
    __shared__ int sh[256];
    int t = threadIdx.x, i = blockIdx.x * 256 + t;
    int v = (i < NN) ? deg[i] : 0;
    sh[t] = v;
    __syncthreads();
    for (int off = 1; off < 256; off <<= 1) {
        int u = (t >= off) ? sh[t - off] : 0;
        __syncthreads();
        sh[t] += u;
        __syncthreads();
    }
    if (i < NN) loc[i] = sh[t] - v;
    if (t == 255) bsum[blockIdx.x] = sh[255];
}

__global__ __launch_bounds__(256) void k_scanB(const int* __restrict__ bsum,
                                               int* __restrict__ boff) {
    __shared__ int sh[256];
    int t = threadIdx.x;
    int v = (t < SCAN_B) ? bsum[t] : 0;
    sh[t] = v;
    __syncthreads();
    for (int off = 1; off < 256; off <<= 1) {
        int u = (t >= off) ? sh[t - off] : 0;
        __syncthreads();
        sh[t] += u;
        __syncthreads();
    }
    if (t < SCAN_B) boff[t] = sh[t] - v;
}

__global__ __launch_bounds__(256) void k_scanC(const int* __restrict__ loc,
                                               const int* __restrict__ boff,
                                               int* __restrict__ rowptr,
                                               int* __restrict__ cursor) {
    int t = threadIdx.x, i = blockIdx.x * 256 + t;
    if (i < NN) {
        int r = loc[i] + boff[blockIdx.x];
        rowptr[i] = r;
        cursor[i] = r;
    }
    if (i == 0) rowptr[NN] = EE;
}

__global__ __launch_bounds__(256) void k_fill(const int* __restrict__ ei,
                                              int* __restrict__ cursor,
                                              int2* __restrict__ es) {
    int i = blockIdx.x * 256 + threadIdx.x;
    if (i < EE) {
        int d = ei[EE + i];
        int pos = atomicAdd(&cursor[d], 1);
        es[pos] = make_int2(ei[i], i);   // (src, edge-id)
    }
}

// ---------- K0: Wqe = Wq @ We^T, bqe = bq @ We^T ----------
__global__ __launch_bounds__(64) void fuse_weights(
    const float* __restrict__ Wq, const float* __restrict__ We,
    const float* __restrict__ bq, float* __restrict__ Wqe,
    float* __restrict__ bqe) {
    int j = threadIdx.x;
    int t = blockIdx.x;
    if (t < 64) {
        float acc = 0.f;
        #pragma unroll
        for (int d = 0; d < 64; ++d) acc = fmaf(Wq[t * 64 + d], We[j * 64 + d], acc);
        Wqe[t * 64 + j] = acc;
    } else {
        float acc = 0.f;
        #pragma unroll
        for (int d = 0; d < 64; ++d) acc = fmaf(bq[d], We[j * 64 + d], acc);
        bqe[j] = acc;
    }
}

// ---------- K1: register-blocked node linear ----------
// 5 waves/block; wave w owns one 64x64 matrix entirely in VGPRs (lane = column).
// Block stages relu(x) for NPB nodes in LDS; each wave streams its GEMV over
// all nodes with same-address (broadcast) ds_read_b128 loads of r.
__global__ __launch_bounds__(NLT) void node_linear(
    const float* __restrict__ hin,
    const float* __restrict__ Wq, const float* __restrict__ Wk,
    const float* __restrict__ Wv, const float* __restrict__ Wsk,
    const float* __restrict__ Wqe,
    const float* __restrict__ bq, const float* __restrict__ bk,
    const float* __restrict__ bv, const float* __restrict__ bs,
    const float* __restrict__ bqe,
    float* __restrict__ q, float* __restrict__ k, float* __restrict__ v,
    float* __restrict__ skip, float* __restrict__ qe) {
    __shared__ float rt[NPB * 64];
    int tid = threadIdx.x;
    int n0 = blockIdx.x * NPB;
    int cnt = min(NPB, NN - n0);

    // cooperative vectorized load + relu
    const float4* hin4 = (const float4*)hin + (size_t)n0 * 16;
    float4* rt4 = (float4*)rt;
    int tot4 = cnt * 16;
    for (int i = tid; i < tot4; i += NLT) {
        float4 xv = hin4[i];
        rt4[i] = make_float4(fmaxf(xv.x, 0.f), fmaxf(xv.y, 0.f),
                             fmaxf(xv.z, 0.f), fmaxf(xv.w, 0.f));
    }
    __syncthreads();

    int wid = tid >> 6, lane = tid & 63;
    const float* Wsel = wid == 0 ? Wq : wid == 1 ? Wk : wid == 2 ? Wv
                      : wid == 3 ? Wsk : Wqe;
    const float* bsel = wid == 0 ? bq : wid == 1 ? bk : wid == 2 ? bv
                      : wid == 3 ? bs : bqe;
    float*       osel = wid == 0 ? q  : wid == 1 ? k  : wid == 2 ? v
                      : wid == 3 ? skip : qe;
    float bias = bsel[lane];

    // weight column `lane` into registers: w[jj] = W[4jj..4jj+3][lane]
    float4 w[16];
    #pragma unroll
    for (int jj = 0; jj < 16; ++jj) {
        w[jj].x = Wsel[(jj * 4 + 0) * 64 + lane];
        w[jj].y = Wsel[(jj * 4 + 1) * 64 + lane];
        w[jj].z = Wsel[(jj * 4 + 2) * 64 + lane];
        w[jj].w = Wsel[(jj * 4 + 3) * 64 + lane];
    }

    for (int b = 0; b < cnt; b += 2) {
        bool has1 = (b + 1) < cnt;
        const float4* r0 = (const float4*)&rt[b * 64];
        const float4* r1 = (const float4*)&rt[(has1 ? b + 1 : b) * 64];
        float a0 = bias, a0b = 0.f, a1 = bias, a1b = 0.f;  // 4 indep chains
        #pragma unroll
        for (int jj = 0; jj < 16; jj += 2) {
            float4 rb0 = r0[jj],     rb1 = r1[jj];
            float4 rc0 = r0[jj + 1], rc1 = r1[jj + 1];
            a0  = fmaf(rb0.x, w[jj].x, a0);
            a0  = fmaf(rb0.y, w[jj].y, a0);
            a0  = fmaf(rb0.z, w[jj].z, a0);
            a0  = fmaf(rb0.w, w[jj].w, a0);
            a0b = fmaf(rc0.x, w[jj + 1].x, a0b);
            a0b = fmaf(rc0.y, w[jj + 1].y, a0b);
            a0b = fmaf(rc0.z, w[jj + 1].z, a0b);
            a0b = fmaf(rc0.w, w[jj + 1].w, a0b);
            a1  = fmaf(rb1.x, w[jj].x, a1);
            a1  = fmaf(rb1.y, w[jj].y, a1);
            a1  = fmaf(rb1.z, w[jj].z, a1);
            a1  = fmaf(rb1.w, w[jj].w, a1);
            a1b = fmaf(rc1.x, w[jj + 1].x, a1b);
            a1b = fmaf(rc1.y, w[jj + 1].y, a1b);
            a1b = fmaf(rc1.z, w[jj + 1].z, a1b);
            a1b = fmaf(rc1.w, w[jj + 1].w, a1b);
        }
        osel[(size_t)(n0 + b) * 64 + lane] = a0 + a0b;
        if (has1) osel[(size_t)(n0 + b + 1) * 64 + lane] = a1 + a1b;
    }
}

__device__ __forceinline__ float dot4(float4 a, float4 b) {
    return fmaf(a.x, b.x, fmaf(a.y, b.y, fmaf(a.z, b.z, a.w * b.w)));
}
__device__ __forceinline__ float4 f4scale(float4 a, float s) {
    return make_float4(a.x * s, a.y * s, a.z * s, a.w * s);
}
__device__ __forceinline__ float4 f4fma(float s, float4 a, float4 acc) {
    return make_float4(fmaf(s, a.x, acc.x), fmaf(s, a.y, acc.y),
                       fmaf(s, a.z, acc.z), fmaf(s, a.w, acc.w));
}
__device__ __forceinline__ float4 f4shflxor_add(float4 a, int mask) {
    a.x += __shfl_xor(a.x, mask);
    a.y += __shfl_xor(a.y, mask);
    a.z += __shfl_xor(a.z, mask);
    a.w += __shfl_xor(a.w, mask);
    return a;
}

// ---------- K2: fused per-node attention, 4 edges/iter (16 lanes each) ----------
__global__ __launch_bounds__(256) void node_attn(
    const int* __restrict__ rowptr, const int2* __restrict__ es,
    const float* __restrict__ ea, const float* __restrict__ q,
    const float* __restrict__ k, const float* __restrict__ v,
    const float* __restrict__ qe, const float* __restrict__ skip,
    const float* __restrict__ We, const float* __restrict__ addx,
    float* __restrict__ out) {
    __shared__ float shA[4][64];   // sum a*v
    __shared__ float shE[4][64];   // sum a*ea
    int wid = threadIdx.x >> 6, lane = threadIdx.x & 63;
    int g = lane >> 4, li = lane & 15;
    int n = blockIdx.x * 4 + wid;
    int beg = rowptr[n], end = rowptr[n + 1];

    const float4* q4  = (const float4*)q;
    const float4* qe4 = (const float4*)qe;
    const float4* k4  = (const float4*)k;
    const float4* v4  = (const float4*)v;
    const float4* ea4 = (const float4*)ea;

    float4 qd  = q4 [(size_t)n * 16 + li];
    float4 qed = qe4[(size_t)n * 16 + li];

    float m = -3.0e38f, den = 0.f;
    float4 av = make_float4(0, 0, 0, 0), ae = make_float4(0, 0, 0, 0);

    if (beg < end) {
        bool vldc; float4 kvc, vvc, evc;
        {
            int idx = beg + g; vldc = idx < end; int ci = vldc ? idx : beg;
            int2 se = es[ci];
            kvc = k4[(size_t)se.x * 16 + li];
            vvc = v4[(size_t)se.x * 16 + li];
            evc = ea4[(size_t)se.y * 16 + li];
        }
        for (int p = beg; p < end; p += 4) {
            bool vldn = false; float4 kvn, vvn, evn;
            if (p + 4 < end) {
                int idx = p + 4 + g; vldn = idx < end; int ci = vldn ? idx : beg;
                int2 se = es[ci];
                kvn = k4[(size_t)se.x * 16 + li];
                vvn = v4[(size_t)se.x * 16 + li];
                evn = ea4[(size_t)se.y * 16 + li];
            }
            float t = dot4(qd, kvc) + dot4(qed, evc);
            t += __shfl_xor(t, 1);
            t += __shfl_xor(t, 2);
            t += __shfl_xor(t, 4);
            t += __shfl_xor(t, 8);
            float lg = vldc ? t * 0.125f : -INFINITY;
            float mx = fmaxf(lg, __shfl_xor(lg, 16));
            mx = fmaxf(mx, __shfl_xor(mx, 32));
            if (mx > m) {
                float sc = __expf(m - mx);
                den *= sc; av = f4scale(av, sc); ae = f4scale(ae, sc);
                m = mx;
            }
            float a = __expf(lg - m);
            den += a;
            av = f4fma(a, vvc, av);
            ae = f4fma(a, evc, ae);
            vldc = vldn; kvc = kvn; vvc = vvn; evc = evn;
        }
    }
    av = f4shflxor_add(av, 16); av = f4shflxor_add(av, 32);
    ae = f4shflxor_add(ae, 16); ae = f4shflxor_add(ae, 32);
    den += __shfl_xor(den, 16); den += __shfl_xor(den, 32);
    if (lane < 16) {
        *(float4*)&shA[wid][lane * 4] = av;
        *(float4*)&shE[wid][lane * 4] = ae;
    }
    __syncthreads();
    float r = 0.f;
    #pragma unroll 8
    for (int j = 0; j < 64; ++j) r = fmaf(shE[wid][j], We[j * 64 + lane], r);
    size_t no = (size_t)n * 64 + lane;
    float o = (den > 0.f) ? (shA[wid][lane] + r) / den : 0.f;
    o += skip[no];
    if (addx) o += addx[no];
    out[no] = o;
}

extern "C" void kernel_launch(void* const* d_in, const int* in_sizes, int n_in,
                              void* d_out, int out_size, void* d_ws, size_t ws_size,
                              hipStream_t stream) {
    const float* x  = (const float*)d_in[0];
    const int*   ei = (const int*)d_in[1];
    const float* ea = (const float*)d_in[2];
    const float* W[10];
    for (int i = 0; i < 10; ++i) W[i] = (const float*)d_in[3 + i];
    const float* B[8];
    for (int i = 0; i < 8; ++i) B[i] = (const float*)d_in[13 + i];

    const size_t ND = (size_t)NN * 64;
    float* ws   = (float*)d_ws;
    float* q    = ws;
    float* k    = ws + 1 * ND;
    float* v    = ws + 2 * ND;
    float* skip = ws + 3 * ND;
    float* qe   = ws + 4 * ND;
    float* h    = ws + 5 * ND;
    int* deg    = (int*)(ws + 6 * ND);   // NN
    int* loc    = deg + NN;              // NN
    int* bsum   = loc + NN;              // 256
    int* boff   = bsum + 256;            // 256
    int* rowptr = boff + 256;            // NN+1
    int* cursor = rowptr + NN + 1;       // NN (+1 pad keeps es 8B-aligned)
    int2* es    = (int2*)(cursor + NN + 1); // EE int2
    float* Wqe  = (float*)(es + EE);     // 4096
    float* bqe  = Wqe + 4096;            // 64

    // ---- build CSR (inputs re-poisoned every call, so rebuild) ----
    (void)hipMemsetAsync(deg, 0, NN * sizeof(int), stream);
    k_hist <<<(EE + 255) / 256, 256, 0, stream>>>(ei, deg);
    k_scanA<<<SCAN_B, 256, 0, stream>>>(deg, loc, bsum);
    k_scanB<<<1, 256, 0, stream>>>(bsum, boff);
    k_scanC<<<SCAN_B, 256, 0, stream>>>(loc, boff, rowptr, cursor);
    k_fill <<<(EE + 255) / 256, 256, 0, stream>>>(ei, cursor, es);

    for (int l = 0; l < 2; ++l) {
        const float* Wq = W[l * 5 + 0], *Wk = W[l * 5 + 1], *Wv = W[l * 5 + 2];
        const float* We = W[l * 5 + 3], *Wsk = W[l * 5 + 4];
        const float* bq = B[l * 4 + 0], *bk = B[l * 4 + 1];
        const float* bv = B[l * 4 + 2], *bs = B[l * 4 + 3];

        fuse_weights<<<65, 64, 0, stream>>>(Wq, We, bq, Wqe, bqe);
        node_linear<<<(NN + NPB - 1) / NPB, NLT, 0, stream>>>(
            l ? h : x, Wq, Wk, Wv, Wsk, Wqe, bq, bk, bv, bs, bqe,
            q, k, v, skip, qe);
        node_attn<<<NN / 4, 256, 0, stream>>>(
            rowptr, es, ea, q, k, v, qe, skip, We,
            l ? x : nullptr, l ? (float*)d_out : h);
    }
}